// Round 3
// baseline (403.096 us; speedup 1.0000x reference)
//
#include <hip/hip_runtime.h>
#include <hip/hip_bf16.h>
#include <stdint.h>

#define DIM 1024
#define NH 16
#define NKV 4
#define HD 64
#define KV_DIM 256
#define SEQ 2048
#define BATCH 2
#define RANK 4
#define NSTEPS 2
#define MASKF (-3.0e38f)

typedef unsigned short u16;
typedef unsigned int u32;
typedef __attribute__((ext_vector_type(8))) __bf16 bf16x8;
typedef __attribute__((ext_vector_type(4))) float f32x4;

__device__ __forceinline__ float bf2f(u16 v) {
    u32 u = ((u32)v) << 16;
    return __builtin_bit_cast(float, u);
}
__device__ __forceinline__ u16 f2bf(float f) {
    u32 u = __builtin_bit_cast(u32, f);
    u32 r = (u + 0x7fffu + ((u >> 16) & 1u)) >> 16;
    return (u16)r;
}
__device__ __forceinline__ u32 pk2(float a, float b) {
    return (u32)f2bf(a) | ((u32)f2bf(b) << 16);
}

// ---------------- K0: t = x @ A^T for LoRA q and v (rank 4), fp32 in/out ----
__global__ __launch_bounds__(256) void k_lora_t(
    const float* __restrict__ x, const float* __restrict__ Aq, const float* __restrict__ Av,
    const int* __restrict__ step_p, float* __restrict__ tq, float* __restrict__ tv)
{
    int wave = (blockIdx.x * 256 + threadIdx.x) >> 6;   // row 0..4095
    int lane = threadIdx.x & 63;
    int step = step_p[0];
    int valid = (step >= 0 && step < NSTEPS);
    int sc = valid ? step : 0;
    const float* xr = x + wave * DIM + lane * 16;
    float xf[16];
#pragma unroll
    for (int q = 0; q < 4; q++) {
        float4 v4 = *(const float4*)(xr + q * 4);
        xf[q * 4 + 0] = v4.x; xf[q * 4 + 1] = v4.y;
        xf[q * 4 + 2] = v4.z; xf[q * 4 + 3] = v4.w;
    }
    float sums[8];
#pragma unroll
    for (int j = 0; j < 8; j++) {
        const float* ar = (j < 4 ? Aq + sc * RANK * DIM + j * DIM
                                 : Av + sc * RANK * DIM + (j - 4) * DIM) + lane * 16;
        float s = 0.f;
#pragma unroll
        for (int q = 0; q < 4; q++) {
            float4 a4 = *(const float4*)(ar + q * 4);
            s += xf[q * 4 + 0] * a4.x + xf[q * 4 + 1] * a4.y
               + xf[q * 4 + 2] * a4.z + xf[q * 4 + 3] * a4.w;
        }
#pragma unroll
        for (int o = 32; o > 0; o >>= 1) s += __shfl_xor(s, o, 64);
        sums[j] = s;
    }
    if (!valid) {
#pragma unroll
        for (int j = 0; j < 8; j++) sums[j] = 0.f;
    }
    if (lane == 0) {
        tq[wave * 4 + 0] = sums[0]; tq[wave * 4 + 1] = sums[1];
        tq[wave * 4 + 2] = sums[2]; tq[wave * 4 + 3] = sums[3];
        tv[wave * 4 + 0] = sums[4]; tv[wave * 4 + 1] = sums[5];
        tv[wave * 4 + 2] = sums[6]; tv[wave * 4 + 3] = sums[7];
    }
}

// ---------------- GEMM: C[M][N] = A[M][1024] * W[N][1024]^T ------------------
// A: fp32 (AF32) or bf16; W: fp32 (converted to bf16 at staging); C: fp32 or bf16.
// 128x128 block tile, BK=64, frag-linear LDS layout (conflict-free ds_read_b128).
template<bool AF32, bool CF32>
__global__ __launch_bounds__(256) void k_gemm(
    const void* __restrict__ Aptr,
    const float* __restrict__ B0, const float* __restrict__ B1, const float* __restrict__ B2,
    int n1, int n2,
    void* __restrict__ Cptr, int Ntiles, int N)
{
    __shared__ __align__(16) u16 As[8192];
    __shared__ __align__(16) u16 Bs[8192];
    int bx = blockIdx.x;
    int bn = bx % Ntiles, bm = bx / Ntiles;
    int t = threadIdx.x, lane = t & 63, w = t >> 6;
    int wy = w >> 1, wx = w & 1;
    f32x4 acc[4][4];
#pragma unroll
    for (int i = 0; i < 4; i++)
#pragma unroll
        for (int j = 0; j < 4; j++) acc[i][j] = (f32x4){0.f, 0.f, 0.f, 0.f};

    for (int kb = 0; kb < 16; kb++) {
        __syncthreads();
#pragma unroll
        for (int u = 0; u < 4; u++) {
            int idx = u * 256 + t;          // 0..1023 frag-linear chunk id
            int grp = idx >> 6;             // mt*2 + c
            int mt = grp >> 1, c = grp & 1;
            int quad = (idx >> 4) & 3, m = idx & 15;
            int row = mt * 16 + m;
            int k0 = kb * 64 + c * 32 + quad * 8;
            // A chunk
            if (AF32) {
                const float* ga = (const float*)Aptr + (bm * 128 + row) * DIM + k0;
                float4 a0 = *(const float4*)ga;
                float4 a1 = *(const float4*)(ga + 4);
                uint4 pkv = make_uint4(pk2(a0.x, a0.y), pk2(a0.z, a0.w),
                                       pk2(a1.x, a1.y), pk2(a1.z, a1.w));
                *(uint4*)(As + idx * 8) = pkv;
            } else {
                const u16* ga = (const u16*)Aptr + (bm * 128 + row) * DIM + k0;
                *(uint4*)(As + idx * 8) = *(const uint4*)ga;
            }
            // B chunk (weights always fp32 row-major [N][1024])
            int brow = bn * 128 + row;
            const float* gb;
            if (brow < n1) gb = B0 + brow * DIM;
            else if (brow < n2) gb = B1 + (brow - n1) * DIM;
            else gb = B2 + (brow - n2) * DIM;
            float4 b0 = *(const float4*)(gb + k0);
            float4 b1 = *(const float4*)(gb + k0 + 4);
            uint4 pkb = make_uint4(pk2(b0.x, b0.y), pk2(b0.z, b0.w),
                                   pk2(b1.x, b1.y), pk2(b1.z, b1.w));
            *(uint4*)(Bs + idx * 8) = pkb;
        }
        __syncthreads();
#pragma unroll
        for (int c = 0; c < 2; c++) {
            bf16x8 af[4], bfr[4];
#pragma unroll
            for (int i = 0; i < 4; i++) {
                int mt = wy * 4 + i;
                af[i] = *(bf16x8*)(As + ((mt * 2 + c) * 64 + lane) * 8);
                int nt = wx * 4 + i;
                bfr[i] = *(bf16x8*)(Bs + ((nt * 2 + c) * 64 + lane) * 8);
            }
#pragma unroll
            for (int i = 0; i < 4; i++)
#pragma unroll
                for (int j = 0; j < 4; j++)
                    acc[i][j] = __builtin_amdgcn_mfma_f32_16x16x32_bf16(af[i], bfr[j], acc[i][j], 0, 0, 0);
        }
    }
    int quad = lane >> 4, n16 = lane & 15;
#pragma unroll
    for (int i = 0; i < 4; i++) {
#pragma unroll
        for (int j = 0; j < 4; j++) {
            int col = bn * 128 + wx * 64 + j * 16 + n16;
#pragma unroll
            for (int r = 0; r < 4; r++) {
                int rowm = bm * 128 + wy * 64 + i * 16 + quad * 4 + r;
                if (CF32) ((float*)Cptr)[rowm * N + col] = acc[i][j][r];
                else      ((u16*)Cptr)[rowm * N + col] = f2bf(acc[i][j][r]);
            }
        }
    }
}

// ---- K2: in-place per-head RMSNorm + partial RoPE (+ LoRA-q add).
// q in qb (bf16, stride 1024), k in kv (bf16, stride 512, cols 0..255).
__global__ __launch_bounds__(256) void k_normrope(
    u16* __restrict__ qb, u16* __restrict__ kv,
    const float* __restrict__ tq, const float* __restrict__ Bq,
    const int* __restrict__ step_p)
{
    int wid = (blockIdx.x * 256 + threadIdx.x) >> 6;
    int lane = threadIdx.x & 63;
    int step = step_p[0];
    int valid = (step >= 0 && step < NSTEPS);
    int sc = valid ? step : 0;
    float val;
    u16* ptr;
    int s;
    if (wid < BATCH * NH * SEQ) {
        int b = wid >> 15;          // / (16*2048)
        int h = (wid >> 11) & 15;
        s = wid & 2047;
        int row = b * SEQ + s;
        ptr = qb + row * DIM + h * HD + lane;
        val = bf2f(*ptr);
        const float* tr = tq + row * 4;
        float4 br = *(const float4*)(Bq + sc * DIM * RANK + (h * HD + lane) * RANK);
        val += tr[0] * br.x + tr[1] * br.y + tr[2] * br.z + tr[3] * br.w;
    } else {
        int wk = wid - BATCH * NH * SEQ;
        int b = wk >> 13;           // / (4*2048)
        int h = (wk >> 11) & 3;     // kv head
        s = wk & 2047;
        int row = b * SEQ + s;
        ptr = kv + row * 512 + h * HD + lane;
        val = bf2f(*ptr);
    }
    // RMS over 64 lanes (fp32 eps, matching fp32 reference semantics)
    float ss = val * val;
#pragma unroll
    for (int o = 32; o > 0; o >>= 1) ss += __shfl_xor(ss, o, 64);
    float rr = rsqrtf(ss * (1.f / 64.f) + 1.1920928955078125e-7f);
    float vn = val * rr;
    // partial RoPE (first 32 dims)
    float partner = __shfl_xor(vn, 16, 64);
    float res;
    if (lane < 32) {
        int i = lane & 15;
        float invf = exp2f(-(float)i * 0.8304820237218405f);  // log2(10000)/16
        float ang = (float)s * invf;
        float cs = cosf(ang), sn = sinf(ang);
        res = (lane < 16) ? (vn * cs + partner * sn) : (-partner * sn + vn * cs);
    } else {
        res = vn;
    }
    *ptr = f2bf(res);
}

// ---------------- KV: v (+LoRA) transpose to vt[b][g][d][S] ----------------
__global__ __launch_bounds__(256) void k_vtrans(
    const u16* __restrict__ kv, const float* __restrict__ tv,
    const float* __restrict__ Bv, const int* __restrict__ step_p,
    u16* __restrict__ vt)
{
    __shared__ __align__(16) u16 tile[64 * 64];
    int bx = blockIdx.x;
    int st = bx & 31, g = (bx >> 5) & 3, b = bx >> 7;
    int t = threadIdx.x;
    int s_l = t & 63, dq = t >> 6;
    int step = step_p[0];
    int valid = (step >= 0 && step < NSTEPS);
    int sc = valid ? step : 0;
    int row = b * SEQ + st * 64 + s_l;
    const float* tr = tv + row * 4;
    float t0 = tr[0], t1 = tr[1], t2 = tr[2], t3 = tr[3];
    const u16* src = kv + row * 512 + KV_DIM + g * HD + dq * 16;
#pragma unroll
    for (int e = 0; e < 16; e++) {
        int d = dq * 16 + e;
        float4 br = *(const float4*)(Bv + sc * KV_DIM * RANK + (g * HD + d) * RANK);
        float v = bf2f(src[e]) + t0 * br.x + t1 * br.y + t2 * br.z + t3 * br.w;
        tile[d * 64 + s_l] = f2bf(v);
    }
    __syncthreads();
#pragma unroll
    for (int u = 0; u < 2; u++) {
        int chunk = u * 256 + t;
        int d = chunk >> 3, scn = chunk & 7;
        *(uint4*)(vt + ((b * NKV + g) * HD + d) * SEQ + st * 64 + scn * 8) =
            *(uint4*)(tile + d * 64 + scn * 8);
    }
}

// ---------------- ATT: flash attention, S^T = K*Q^T orientation -------------
// block: (b, h, 64 q-rows); wave w: 16 q-rows. K/V tiles of 64 keys in LDS.
__global__ __launch_bounds__(256) void k_attn(
    const u16* __restrict__ qb, const u16* __restrict__ kv, const u16* __restrict__ vt,
    const float* __restrict__ gain, u16* __restrict__ y)
{
    __shared__ __align__(16) u16 kf[4096];       // 64 keys x 64 d, A-frag linear
    __shared__ __align__(16) u16 vf[4096];       // 64 d x 64 keys, A-frag linear
    __shared__ __align__(16) u16 pb[4][1024];    // per-wave P^T, B-frag linear
    int bx = blockIdx.x;
    int qt = bx & 31, h = (bx >> 5) & 15, b = bx >> 9;
    int g = h >> 2;
    int t = threadIdx.x, lane = t & 63, w = t >> 6;
    int quad = lane >> 4, n16 = lane & 15;
    int qrow = qt * 64 + w * 16 + n16;
    float sscale = gain[h] * 0.125f * 1.4426950408889634f;  // gain/sqrt(64)*log2(e)
    // Q fragments (B-operand role: lane n16 = q row, 8 contiguous d per quad)
    const u16* qbase = qb + (b * SEQ + qrow) * DIM + h * HD + quad * 8;
    bf16x8 qf0 = *(const bf16x8*)(qbase);
    bf16x8 qf1 = *(const bf16x8*)(qbase + 32);
    f32x4 yacc[4];
#pragma unroll
    for (int i = 0; i < 4; i++) yacc[i] = (f32x4){0.f, 0.f, 0.f, 0.f};
    float m_run = MASKF, l_run = 0.f;
    const u16* kbase = kv + b * SEQ * 512 + g * HD;      // K rows, stride 512
    const u16* vbase = vt + (b * NKV + g) * HD * SEQ;
    u16* pw = pb[w];

    for (int kt = 0; kt <= qt; kt++) {
        int k0 = kt * 64;
        __syncthreads();
#pragma unroll
        for (int u = 0; u < 2; u++) {
            int idx = u * 256 + t;              // 0..511
            int grp = idx >> 6, qd = (idx >> 4) & 3, m = idx & 15;
            int g16 = grp >> 1, c = grp & 1;
            *(uint4*)(kf + idx * 8) =
                *(const uint4*)(kbase + (k0 + g16 * 16 + m) * 512 + c * 32 + qd * 8);
            *(uint4*)(vf + idx * 8) =
                *(const uint4*)(vbase + (g16 * 16 + m) * SEQ + k0 + c * 32 + qd * 8);
        }
        __syncthreads();
        // S^T tiles: D[key][q] — lane holds keys (quad*4+r within 16-group), q col n16
        f32x4 st[4];
#pragma unroll
        for (int nt = 0; nt < 4; nt++) {
            f32x4 sa = (f32x4){0.f, 0.f, 0.f, 0.f};
            sa = __builtin_amdgcn_mfma_f32_16x16x32_bf16(*(bf16x8*)(kf + ((nt * 2 + 0) * 64 + lane) * 8), qf0, sa, 0, 0, 0);
            sa = __builtin_amdgcn_mfma_f32_16x16x32_bf16(*(bf16x8*)(kf + ((nt * 2 + 1) * 64 + lane) * 8), qf1, sa, 0, 0, 0);
            st[nt] = sa;
        }
        // scale (+ gain) in fp32, then causal mask with finite large-negative
#pragma unroll
        for (int nt = 0; nt < 4; nt++)
#pragma unroll
            for (int r = 0; r < 4; r++) st[nt][r] *= sscale;
        if (kt == qt) {
#pragma unroll
            for (int nt = 0; nt < 4; nt++)
#pragma unroll
                for (int r = 0; r < 4; r++) {
                    int key = k0 + nt * 16 + quad * 4 + r;
                    if (key > qrow) st[nt][r] = MASKF;
                }
        }
        // online softmax, per-lane state (q row = n16, replicated across quads)
        float tm = st[0][0];
#pragma unroll
        for (int nt = 0; nt < 4; nt++)
#pragma unroll
            for (int r = 0; r < 4; r++) tm = fmaxf(tm, st[nt][r]);
        tm = fmaxf(tm, __shfl_xor(tm, 16, 64));
        tm = fmaxf(tm, __shfl_xor(tm, 32, 64));
        float m_new = fmaxf(m_run, tm);
        float alpha = exp2f(m_run - m_new);
        m_run = m_new;
        float tsum = 0.f;
        float p[4][4];
#pragma unroll
        for (int nt = 0; nt < 4; nt++)
#pragma unroll
            for (int r = 0; r < 4; r++) {
                float e = exp2f(st[nt][r] - m_new);
                p[nt][r] = e;
                tsum += e;
            }
        tsum += __shfl_xor(tsum, 16, 64);
        tsum += __shfl_xor(tsum, 32, 64);
        l_run = l_run * alpha + tsum;
#pragma unroll
        for (int i = 0; i < 4; i++) {
            yacc[i][0] *= alpha; yacc[i][1] *= alpha;
            yacc[i][2] *= alpha; yacc[i][3] *= alpha;
        }
        // P^T -> per-wave LDS in B-frag linear layout (4 consecutive keys -> one 8B write)
#pragma unroll
        for (int nt = 0; nt < 4; nt++) {
            u32 lo = pk2(p[nt][0], p[nt][1]);
            u32 hi = pk2(p[nt][2], p[nt][3]);
            int ck = nt >> 1;
            int qbk = (nt & 1) * 2 + (quad >> 1);
            int byteoff = (ck * 64 + qbk * 16 + n16) * 16 + (quad & 1) * 8;
            *(uint2*)((char*)pw + byteoff) = make_uint2(lo, hi);
        }
        // same-wave RAW on LDS: force completion + forbid compiler reordering
        asm volatile("s_waitcnt lgkmcnt(0)" ::: "memory");
        // Y^T += V^T * P^T
#pragma unroll
        for (int ck = 0; ck < 2; ck++) {
            bf16x8 pfr = *(bf16x8*)(pw + (ck * 64 + lane) * 8);
#pragma unroll
            for (int dt = 0; dt < 4; dt++) {
                bf16x8 vfr = *(bf16x8*)(vf + ((dt * 2 + ck) * 64 + lane) * 8);
                yacc[dt] = __builtin_amdgcn_mfma_f32_16x16x32_bf16(vfr, pfr, yacc[dt], 0, 0, 0);
            }
        }
        asm volatile("" ::: "memory");
    }
    float linv = 1.f / l_run;
#pragma unroll
    for (int dt = 0; dt < 4; dt++) {
        uint2 pkv = make_uint2(pk2(yacc[dt][0] * linv, yacc[dt][1] * linv),
                               pk2(yacc[dt][2] * linv, yacc[dt][3] * linv));
        int d = dt * 16 + quad * 4;
        *(uint2*)(y + (b * SEQ + qrow) * DIM + h * HD + d) = pkv;
    }
}

// ---------------------------------------------------------------------------
extern "C" void kernel_launch(void* const* d_in, const int* in_sizes, int n_in,
                              void* d_out, int out_size, void* d_ws, size_t ws_size,
                              hipStream_t stream)
{
    (void)in_sizes; (void)n_in; (void)out_size; (void)ws_size;
    const float* x     = (const float*)d_in[0];
    const float* Wq    = (const float*)d_in[1];
    const float* Wk    = (const float*)d_in[2];
    const float* Wv    = (const float*)d_in[3];
    const float* Wproj = (const float*)d_in[4];
    const float* qgain = (const float*)d_in[5];
    const float* Aq    = (const float*)d_in[6];
    const float* Bq    = (const float*)d_in[7];
    const float* Av    = (const float*)d_in[8];
    const float* Bv    = (const float*)d_in[9];
    const int*   step  = (const int*)d_in[10];

    // ws layout (22.13 MB total):
    char* ws = (char*)d_ws;
    float* tq = (float*)ws;                                   // 64 KB
    float* tv = (float*)(ws + (64 << 10));                    // 64 KB
    u16* qb   = (u16*)(ws + (128 << 10));                     // 8 MB  [4096][1024] bf16
    u16* kv   = (u16*)(ws + (128 << 10) + (8u << 20));        // 4 MB  [4096][512] bf16: k|v
    u16* vt   = (u16*)(ws + (128 << 10) + (12u << 20));       // 2 MB  [2][4][64][2048] bf16
    u16* y    = (u16*)(ws + (128 << 10) + (14u << 20));       // 8 MB  [4096][1024] bf16

    k_gemm<true, false><<<256, 256, 0, stream>>>(x, Wq, Wq, Wq, 1024, 1024, qb, 8, DIM);  // q
    k_gemm<true, false><<<128, 256, 0, stream>>>(x, Wk, Wv, Wv, 256, 512, kv, 4, 512);    // k|v
    k_lora_t<<<1024, 256, 0, stream>>>(x, Aq, Av, step, tq, tv);
    k_normrope<<<20480, 256, 0, stream>>>(qb, kv, tq, Bq, step);
    k_vtrans<<<256, 256, 0, stream>>>(kv, tv, Bv, step, vt);
    k_attn<<<1024, 256, 0, stream>>>(qb, kv, vt, qgain, y);
    k_gemm<false, true><<<256, 256, 0, stream>>>(y, Wproj, Wproj, Wproj, 1024, 1024, d_out, 8, DIM);
}

// Round 4
// 307.847 us; speedup vs baseline: 1.3094x; 1.3094x over previous
//
#include <hip/hip_runtime.h>
#include <hip/hip_bf16.h>
#include <stdint.h>

#define DIM 1024
#define NH 16
#define NKV 4
#define HD 64
#define SEQ 2048
#define BATCH 2
#define RANK 4
#define NSTEPS 2
#define MASKF (-3.0e38f)

// bf16 conversion-region element offsets (compile-time)
#define XN      4194304            // x: 4096*1024
#define WQ_END  5242880            // + 1024*1024
#define WK_END  5505024            // + 256*1024
#define WV_END  5767168            // + 256*1024
#define CVT_TOT 6815744            // + 1024*1024

typedef unsigned short u16;
typedef unsigned int u32;
typedef __attribute__((ext_vector_type(8))) __bf16 bf16x8;
typedef __attribute__((ext_vector_type(4))) float f32x4;

__device__ __forceinline__ float bf2f(u16 v) {
    u32 u = ((u32)v) << 16;
    return __builtin_bit_cast(float, u);
}
__device__ __forceinline__ u16 f2bf(float f) {
    u32 u = __builtin_bit_cast(u32, f);
    u32 r = (u + 0x7fffu + ((u >> 16) & 1u)) >> 16;
    return (u16)r;
}
__device__ __forceinline__ u32 pk2(float a, float b) {
    return (u32)f2bf(a) | ((u32)f2bf(b) << 16);
}

// ---------------- K-1: fp32 -> bf16 one-shot convert [x|Wq|Wk|Wv|Wproj] ------
__global__ __launch_bounds__(256) void k_convert(
    const float* __restrict__ x, const float* __restrict__ Wq,
    const float* __restrict__ Wk, const float* __restrict__ Wv,
    const float* __restrict__ Wp, u16* __restrict__ dst)
{
    int e = (blockIdx.x * 256 + threadIdx.x) * 4;
    const float* src;
    if (e < XN)          src = x  + e;
    else if (e < WQ_END) src = Wq + (e - XN);
    else if (e < WK_END) src = Wk + (e - WQ_END);
    else if (e < WV_END) src = Wv + (e - WK_END);
    else                 src = Wp + (e - WV_END);
    float4 v = *(const float4*)src;
    *(uint2*)(dst + e) = make_uint2(pk2(v.x, v.y), pk2(v.z, v.w));
}

// ---------------- K0: t = x @ A^T for LoRA q and v (rank 4), fp32 in/out ----
__global__ __launch_bounds__(256) void k_lora_t(
    const float* __restrict__ x, const float* __restrict__ Aq, const float* __restrict__ Av,
    const int* __restrict__ step_p, float* __restrict__ tq, float* __restrict__ tv)
{
    int wave = (blockIdx.x * 256 + threadIdx.x) >> 6;   // row 0..4095
    int lane = threadIdx.x & 63;
    int step = step_p[0];
    int valid = (step >= 0 && step < NSTEPS);
    int sc = valid ? step : 0;
    const float* xr = x + wave * DIM + lane * 16;
    float xf[16];
#pragma unroll
    for (int q = 0; q < 4; q++) {
        float4 v4 = *(const float4*)(xr + q * 4);
        xf[q * 4 + 0] = v4.x; xf[q * 4 + 1] = v4.y;
        xf[q * 4 + 2] = v4.z; xf[q * 4 + 3] = v4.w;
    }
    float sums[8];
#pragma unroll
    for (int j = 0; j < 8; j++) {
        const float* ar = (j < 4 ? Aq + sc * RANK * DIM + j * DIM
                                 : Av + sc * RANK * DIM + (j - 4) * DIM) + lane * 16;
        float s = 0.f;
#pragma unroll
        for (int q = 0; q < 4; q++) {
            float4 a4 = *(const float4*)(ar + q * 4);
            s += xf[q * 4 + 0] * a4.x + xf[q * 4 + 1] * a4.y
               + xf[q * 4 + 2] * a4.z + xf[q * 4 + 3] * a4.w;
        }
#pragma unroll
        for (int o = 32; o > 0; o >>= 1) s += __shfl_xor(s, o, 64);
        sums[j] = s;
    }
    if (!valid) {
#pragma unroll
        for (int j = 0; j < 8; j++) sums[j] = 0.f;
    }
    if (lane == 0) {
        tq[wave * 4 + 0] = sums[0]; tq[wave * 4 + 1] = sums[1];
        tq[wave * 4 + 2] = sums[2]; tq[wave * 4 + 3] = sums[3];
        tv[wave * 4 + 0] = sums[4]; tv[wave * 4 + 1] = sums[5];
        tv[wave * 4 + 2] = sums[6]; tv[wave * 4 + 3] = sums[7];
    }
}

// ---------------- GEMM: C[M][N] = A[M][1024] * B[N][1024]^T, bf16 in, fp32 acc
// 128x128 block tile, BK=64, frag-linear LDS layout (conflict-free ds_read_b128)
template<bool CF32>
__global__ __launch_bounds__(256) void k_gemm(
    const u16* __restrict__ A, const u16* __restrict__ B,
    void* __restrict__ Cptr, int Ntiles, int N)
{
    __shared__ __align__(16) u16 As[8192];
    __shared__ __align__(16) u16 Bs[8192];
    int bx = blockIdx.x;
    int bn = bx % Ntiles, bm = bx / Ntiles;
    int t = threadIdx.x, lane = t & 63, w = t >> 6;
    int wy = w >> 1, wx = w & 1;
    f32x4 acc[4][4];
#pragma unroll
    for (int i = 0; i < 4; i++)
#pragma unroll
        for (int j = 0; j < 4; j++) acc[i][j] = (f32x4){0.f, 0.f, 0.f, 0.f};

    for (int kb = 0; kb < 16; kb++) {
        __syncthreads();
#pragma unroll
        for (int u = 0; u < 4; u++) {
            int idx = u * 256 + t;          // 0..1023 frag-linear chunk id
            int grp = idx >> 6;             // mt*2 + c
            int mt = grp >> 1, c = grp & 1;
            int quad = (idx >> 4) & 3, m = idx & 15;
            int row = mt * 16 + m;
            int k0 = kb * 64 + c * 32 + quad * 8;
            *(uint4*)(As + idx * 8) = *(const uint4*)(A + (bm * 128 + row) * DIM + k0);
            *(uint4*)(Bs + idx * 8) = *(const uint4*)(B + (bn * 128 + row) * DIM + k0);
        }
        __syncthreads();
#pragma unroll
        for (int c = 0; c < 2; c++) {
            bf16x8 af[4], bfr[4];
#pragma unroll
            for (int i = 0; i < 4; i++) {
                int mt = wy * 4 + i;
                af[i] = *(bf16x8*)(As + ((mt * 2 + c) * 64 + lane) * 8);
                int nt = wx * 4 + i;
                bfr[i] = *(bf16x8*)(Bs + ((nt * 2 + c) * 64 + lane) * 8);
            }
#pragma unroll
            for (int i = 0; i < 4; i++)
#pragma unroll
                for (int j = 0; j < 4; j++)
                    acc[i][j] = __builtin_amdgcn_mfma_f32_16x16x32_bf16(af[i], bfr[j], acc[i][j], 0, 0, 0);
        }
    }
    int quad = lane >> 4, n16 = lane & 15;
#pragma unroll
    for (int i = 0; i < 4; i++) {
#pragma unroll
        for (int j = 0; j < 4; j++) {
            int col = bn * 128 + wx * 64 + j * 16 + n16;
#pragma unroll
            for (int r = 0; r < 4; r++) {
                int rowm = bm * 128 + wy * 64 + i * 16 + quad * 4 + r;
                if (CF32) ((float*)Cptr)[rowm * N + col] = acc[i][j][r];
                else      ((u16*)Cptr)[rowm * N + col] = f2bf(acc[i][j][r]);
            }
        }
    }
}

// ---- K2: in-place per-head RMSNorm + partial RoPE (+ LoRA-q add + gain fold).
// q cols 0..1023 and k cols 1024..1279 of qkv (bf16, row stride 1536).
__global__ __launch_bounds__(256) void k_normrope(
    u16* __restrict__ qkv,
    const float* __restrict__ tq, const float* __restrict__ Bq,
    const float* __restrict__ gain, const int* __restrict__ step_p)
{
    int wid = (blockIdx.x * 256 + threadIdx.x) >> 6;
    int lane = threadIdx.x & 63;
    int step = step_p[0];
    int valid = (step >= 0 && step < NSTEPS);
    int sc = valid ? step : 0;
    float val, postmul;
    u16* ptr;
    int s;
    if (wid < BATCH * NH * SEQ) {
        int b = wid >> 15;          // / (16*2048)
        int h = (wid >> 11) & 15;
        s = wid & 2047;
        int row = b * SEQ + s;
        ptr = qkv + row * 1536 + h * HD + lane;
        val = bf2f(*ptr);
        const float* tr = tq + row * 4;
        float4 br = *(const float4*)(Bq + sc * DIM * RANK + (h * HD + lane) * RANK);
        val += tr[0] * br.x + tr[1] * br.y + tr[2] * br.z + tr[3] * br.w;
        // fold gain/sqrt(64)*log2e into q (exp2-domain softmax downstream)
        postmul = gain[h] * 0.125f * 1.4426950408889634f;
    } else {
        int wk = wid - BATCH * NH * SEQ;
        int b = wk >> 13;           // / (4*2048)
        int h = (wk >> 11) & 3;     // kv head
        s = wk & 2047;
        int row = b * SEQ + s;
        ptr = qkv + row * 1536 + 1024 + h * HD + lane;
        val = bf2f(*ptr);
        postmul = 1.f;
    }
    // RMS over 64 lanes (fp32 eps, matching fp32 reference semantics)
    float ss = val * val;
#pragma unroll
    for (int o = 32; o > 0; o >>= 1) ss += __shfl_xor(ss, o, 64);
    float rr = rsqrtf(ss * (1.f / 64.f) + 1.1920928955078125e-7f);
    float vn = val * rr;
    // partial RoPE (first 32 dims)
    float partner = __shfl_xor(vn, 16, 64);
    float res;
    if (lane < 32) {
        int i = lane & 15;
        float invf = exp2f(-(float)i * 0.8304820237218405f);  // log2(10000)/16
        float ang = (float)s * invf;
        float cs = cosf(ang), sn = sinf(ang);
        res = (lane < 16) ? (vn * cs + partner * sn) : (-partner * sn + vn * cs);
    } else {
        res = vn;
    }
    *ptr = f2bf(res * postmul);
}

// ---------------- KV: v (+LoRA) transpose to vt[b][g][d][S] ----------------
__global__ __launch_bounds__(256) void k_vtrans(
    const u16* __restrict__ qkv, const float* __restrict__ tv,
    const float* __restrict__ Bv, const int* __restrict__ step_p,
    u16* __restrict__ vt)
{
    __shared__ __align__(16) u16 tile[64 * 64];
    int bx = blockIdx.x;
    int st = bx & 31, g = (bx >> 5) & 3, b = bx >> 7;
    int t = threadIdx.x;
    int s_l = t & 63, dq = t >> 6;
    int step = step_p[0];
    int valid = (step >= 0 && step < NSTEPS);
    int sc = valid ? step : 0;
    int row = b * SEQ + st * 64 + s_l;
    const float* tr = tv + row * 4;
    float t0 = tr[0], t1 = tr[1], t2 = tr[2], t3 = tr[3];
    const u16* src = qkv + row * 1536 + 1280 + g * HD + dq * 16;
#pragma unroll
    for (int e = 0; e < 16; e++) {
        int d = dq * 16 + e;
        float4 br = *(const float4*)(Bv + sc * (NKV * HD) * RANK + (g * HD + d) * RANK);
        float v = bf2f(src[e]) + t0 * br.x + t1 * br.y + t2 * br.z + t3 * br.w;
        tile[d * 64 + s_l] = f2bf(v);
    }
    __syncthreads();
#pragma unroll
    for (int u = 0; u < 2; u++) {
        int chunk = u * 256 + t;
        int d = chunk >> 3, scn = chunk & 7;
        *(uint4*)(vt + ((b * NKV + g) * HD + d) * SEQ + st * 64 + scn * 8) =
            *(uint4*)(tile + d * 64 + scn * 8);
    }
}

// ---------------- ATT: barrier-free flash attention, S^T = K*Q^T ------------
// 512 blocks x 4 waves. Wave gw owns q-strips (pr, 127-pr) of 16 rows each for
// one (b,h) -> exactly 33+-1 K-tile iterations per wave (flat load balance).
// K/V fragments loaded directly global->VGPR (L2-served); only P^T uses LDS.
__global__ __launch_bounds__(256, 3) void k_attn(
    const u16* __restrict__ qkv, const u16* __restrict__ vt,
    u16* __restrict__ y)
{
    __shared__ __align__(16) u16 pb[4][1024];    // per-wave P^T, B-frag linear
    int w = threadIdx.x >> 6, lane = threadIdx.x & 63;
    int gw = blockIdx.x * 4 + w;
    int b = gw >> 10, h = (gw >> 6) & 15, pr = gw & 63;
    int g = h >> 2;
    int quad = lane >> 4, n16 = lane & 15;
    const u16* kbase = qkv + b * SEQ * 1536 + 1024 + g * HD;   // K rows, stride 1536
    const u16* vbase = vt + (b * NKV + g) * HD * SEQ;          // V^T rows, stride 2048
    u16* pw = pb[w];

#pragma unroll 1
    for (int half = 0; half < 2; half++) {
        int strip = half ? (127 - pr) : pr;
        int qrow = strip * 16 + n16;
        // Q fragments (B-operand: lane n16 = q row, k = c*32+quad*8+j)
        const u16* qb = qkv + (b * SEQ + qrow) * 1536 + h * HD + quad * 8;
        bf16x8 qf0 = *(const bf16x8*)qb;
        bf16x8 qf1 = *(const bf16x8*)(qb + 32);
        f32x4 yacc[4];
#pragma unroll
        for (int i = 0; i < 4; i++) yacc[i] = (f32x4){0.f, 0.f, 0.f, 0.f};
        float m_run = MASKF, l_run = 0.f;
        int niter = (strip >> 2) + 1;
#pragma unroll 1
        for (int kt = 0; kt < niter; kt++) {
            int k0 = kt * 64;
            // K A-fragments direct from global (frag (g16,c): key=k0+g16*16+n16, d=c*32+quad*8)
            bf16x8 kfr[8];
#pragma unroll
            for (int g16 = 0; g16 < 4; g16++)
#pragma unroll
                for (int c = 0; c < 2; c++)
                    kfr[g16 * 2 + c] = *(const bf16x8*)(kbase + (k0 + g16 * 16 + n16) * 1536 + c * 32 + quad * 8);
            // V^T A-fragments (frag (dt,c): d=dt*16+n16, key=k0+c*32+quad*8)
            bf16x8 vfr[8];
#pragma unroll
            for (int dt = 0; dt < 4; dt++)
#pragma unroll
                for (int c = 0; c < 2; c++)
                    vfr[dt * 2 + c] = *(const bf16x8*)(vbase + (dt * 16 + n16) * SEQ + k0 + c * 32 + quad * 8);
            // S^T: D[key][q], scale+gain+log2e pre-folded into q
            f32x4 st[4];
#pragma unroll
            for (int nt = 0; nt < 4; nt++) {
                f32x4 sa = (f32x4){0.f, 0.f, 0.f, 0.f};
                sa = __builtin_amdgcn_mfma_f32_16x16x32_bf16(kfr[nt * 2 + 0], qf0, sa, 0, 0, 0);
                sa = __builtin_amdgcn_mfma_f32_16x16x32_bf16(kfr[nt * 2 + 1], qf1, sa, 0, 0, 0);
                st[nt] = sa;
            }
            if (kt == niter - 1) {   // diagonal tile: causal mask (finite large-neg)
#pragma unroll
                for (int nt = 0; nt < 4; nt++)
#pragma unroll
                    for (int r = 0; r < 4; r++) {
                        int key = k0 + nt * 16 + quad * 4 + r;
                        st[nt][r] = (key > qrow) ? MASKF : st[nt][r];
                    }
            }
            // online softmax (exp2 domain), per-lane state for q=n16
            float tm = st[0][0];
#pragma unroll
            for (int nt = 0; nt < 4; nt++)
#pragma unroll
                for (int r = 0; r < 4; r++) tm = fmaxf(tm, st[nt][r]);
            tm = fmaxf(tm, __shfl_xor(tm, 16, 64));
            tm = fmaxf(tm, __shfl_xor(tm, 32, 64));
            float m_new = fmaxf(m_run, tm);
            float alpha = exp2f(m_run - m_new);
            m_run = m_new;
            float tsum = 0.f;
            float p[4][4];
#pragma unroll
            for (int nt = 0; nt < 4; nt++)
#pragma unroll
                for (int r = 0; r < 4; r++) {
                    float e = exp2f(st[nt][r] - m_new);
                    p[nt][r] = e;
                    tsum += e;
                }
            tsum += __shfl_xor(tsum, 16, 64);
            tsum += __shfl_xor(tsum, 32, 64);
            l_run = l_run * alpha + tsum;
#pragma unroll
            for (int i = 0; i < 4; i++) {
                yacc[i][0] *= alpha; yacc[i][1] *= alpha;
                yacc[i][2] *= alpha; yacc[i][3] *= alpha;
            }
            // P^T -> per-wave LDS in B-frag linear layout
#pragma unroll
            for (int nt = 0; nt < 4; nt++) {
                u32 lo = pk2(p[nt][0], p[nt][1]);
                u32 hi = pk2(p[nt][2], p[nt][3]);
                int ck = nt >> 1;
                int qbk = (nt & 1) * 2 + (quad >> 1);
                int byteoff = (ck * 64 + qbk * 16 + n16) * 16 + (quad & 1) * 8;
                *(uint2*)((char*)pw + byteoff) = make_uint2(lo, hi);
            }
            asm volatile("s_waitcnt lgkmcnt(0)" ::: "memory");
            // Y^T += V^T * P^T
#pragma unroll
            for (int ck = 0; ck < 2; ck++) {
                bf16x8 pfr = *(bf16x8*)(pw + (ck * 64 + lane) * 8);
#pragma unroll
                for (int dt = 0; dt < 4; dt++)
                    yacc[dt] = __builtin_amdgcn_mfma_f32_16x16x32_bf16(vfr[dt * 2 + ck], pfr, yacc[dt], 0, 0, 0);
            }
            asm volatile("" ::: "memory");
        }
        float linv = 1.f / l_run;
#pragma unroll
        for (int dt = 0; dt < 4; dt++) {
            uint2 pkv = make_uint2(pk2(yacc[dt][0] * linv, yacc[dt][1] * linv),
                                   pk2(yacc[dt][2] * linv, yacc[dt][3] * linv));
            int d = dt * 16 + quad * 4;
            *(uint2*)(y + (b * SEQ + qrow) * DIM + h * HD + d) = pkv;
        }
    }
}

// ---------------------------------------------------------------------------
extern "C" void kernel_launch(void* const* d_in, const int* in_sizes, int n_in,
                              void* d_out, int out_size, void* d_ws, size_t ws_size,
                              hipStream_t stream)
{
    (void)in_sizes; (void)n_in; (void)out_size; (void)ws_size;
    const float* x     = (const float*)d_in[0];
    const float* Wq    = (const float*)d_in[1];
    const float* Wk    = (const float*)d_in[2];
    const float* Wv    = (const float*)d_in[3];
    const float* Wproj = (const float*)d_in[4];
    const float* qgain = (const float*)d_in[5];
    const float* Aq    = (const float*)d_in[6];
    const float* Bq    = (const float*)d_in[7];
    const float* Av    = (const float*)d_in[8];
    const float* Bv    = (const float*)d_in[9];
    const int*   step  = (const int*)d_in[10];

    // ws layout (25.1 MB):
    //  [0, 13631488)          bf16 cvt region: [xb 8MB | Wqkv 3MB | Wproj 2MB]
    //  [13631488, 26214400)   qkv bf16 [4096][1536] (12 MB)
    //  [26214400, 26345472)   tq, tv fp32 (64 KB each)
    //  reuse: y (8MB) overlays xb (dead after qkv GEMM);
    //         vt (2MB) overlays Wqkv (dead after qkv GEMM).
    char* ws = (char*)d_ws;
    u16* wsbf = (u16*)ws;
    u16* xb   = wsbf;                  // 4194304 elems
    u16* wf   = wsbf + XN;             // fused [Wq|Wk|Wv] 1536x1024
    u16* wp   = wsbf + WV_END;         // Wproj 1024x1024
    u16* qkv  = (u16*)(ws + 13631488); // [4096][1536]
    float* tq = (float*)(ws + 26214400);
    float* tv = tq + 16384;
    u16* y    = xb;                    // reuse
    u16* vt   = wf;                    // reuse: [2][4][64][2048]

    k_convert<<<6656, 256, 0, stream>>>(x, Wq, Wk, Wv, Wproj, wsbf);
    k_lora_t<<<1024, 256, 0, stream>>>(x, Aq, Av, step, tq, tv);
    k_gemm<false><<<384, 256, 0, stream>>>(xb, wf, qkv, 12, 1536);      // fused qkv
    k_normrope<<<20480, 256, 0, stream>>>(qkv, tq, Bq, qgain, step);
    k_vtrans<<<256, 256, 0, stream>>>(qkv, tv, Bv, step, vt);
    k_attn<<<512, 256, 0, stream>>>(qkv, vt, y);
    k_gemm<true><<<256, 256, 0, stream>>>(y, wp, d_out, 8, DIM);        // out proj
}